// Round 1
// baseline (2512.291 us; speedup 1.0000x reference)
//
#include <hip/hip_runtime.h>
#include <math.h>

#define Hd 256
#define Bb 64
#define Tn 2047
#define LEAF0 1023
#define NW 5
#define MT 32

typedef long long i64;

__device__ __forceinline__ float sigm(float x){ return 1.0f/(1.0f+__expf(-x)); }

// Transpose weights to k-major once per launch:
//   WtI[k*1280 + j] : j in [0,768) = U_iou[j][k], j in [768,1280) = U_f_w[j-768][k]   (k<512)
//   WtL[k*768  + j] : W_iou[j][k]                                                    (k<256)
__global__ __launch_bounds__(256)
void wt_kernel(const float* __restrict__ U_iou, const float* __restrict__ U_f_w,
               const float* __restrict__ W_iou,
               float* __restrict__ WtI, float* __restrict__ WtL){
  int idx = blockIdx.x*256 + threadIdx.x;
  if (idx < 512*1280){
    int k = idx/1280, j = idx - k*1280;
    WtI[idx] = (j < 768) ? U_iou[j*512 + k] : U_f_w[(j-768)*512 + k];
  }
  if (idx < 256*768){
    int k = idx/768, j = idx - k*768;
    WtL[idx] = W_iou[j*256 + k];
  }
}

// Leaf nodes: wemb = sum_l emb[wordid[l]]; iou = wemb @ W_iou^T; LSTM leaf update.
// Block: MT=32 leaf rows x 64 h-columns (grid.y=4 covers H=256). 3 strips (i,o,u).
__global__ __launch_bounds__(256)
void leaf_kernel(const int* __restrict__ wordid, const float* __restrict__ emb,
                 const float* __restrict__ Wt, const float* __restrict__ b_iou,
                 const float* __restrict__ c0, float* __restrict__ h, float* __restrict__ cb){
  __shared__ __align__(16) float A[256*MT];   // [k][m], k<256
  const int tid = threadIdx.x;
  {
    const int m = tid >> 3, q = tid & 7;      // 8 threads per row, coalesced 128B runs
    const int mg = blockIdx.x*MT + m;
    const int b = mg >> 10, j = mg & 1023;
    const i64 n = (i64)b*Tn + LEAF0 + j;
    const int* wid = wordid + n*NW;
    const i64 r0=(i64)wid[0]*Hd, r1=(i64)wid[1]*Hd, r2=(i64)wid[2]*Hd,
              r3=(i64)wid[3]*Hd, r4=(i64)wid[4]*Hd;
    #pragma unroll
    for (int i=0;i<8;i++){
      const int k = i*32 + q*4;
      float4 v0 = *(const float4*)(emb + r0 + k);
      float4 v1 = *(const float4*)(emb + r1 + k);
      float4 v2 = *(const float4*)(emb + r2 + k);
      float4 v3 = *(const float4*)(emb + r3 + k);
      float4 v4 = *(const float4*)(emb + r4 + k);
      A[(k+0)*MT+m] = v0.x+v1.x+v2.x+v3.x+v4.x;
      A[(k+1)*MT+m] = v0.y+v1.y+v2.y+v3.y+v4.y;
      A[(k+2)*MT+m] = v0.z+v1.z+v2.z+v3.z+v4.z;
      A[(k+3)*MT+m] = v0.w+v1.w+v2.w+v3.w+v4.w;
    }
  }
  __syncthreads();
  const int tx = tid & 63, ty = tid >> 6;
  const int hh = blockIdx.y*64 + tx;
  float acc0[8], acc1[8], acc2[8];
  #pragma unroll
  for (int r=0;r<8;r++){ acc0[r]=0.f; acc1[r]=0.f; acc2[r]=0.f; }
  const float* wp = Wt + hh;
  #pragma unroll 4
  for (int k=0;k<256;k++){
    const float* wk = wp + k*768;
    const float w0 = wk[0], w1 = wk[256], w2 = wk[512];
    float a[8];
    *(float4*)(a)   = *(const float4*)&A[k*MT + ty*8];
    *(float4*)(a+4) = *(const float4*)&A[k*MT + ty*8 + 4];
    #pragma unroll
    for (int r=0;r<8;r++){
      acc0[r] += a[r]*w0;
      acc1[r] += a[r]*w1;
      acc2[r] += a[r]*w2;
    }
  }
  const float bi = b_iou[hh], bo = b_iou[256+hh], bu = b_iou[512+hh];
  #pragma unroll
  for (int r=0;r<8;r++){
    const int mg = blockIdx.x*MT + ty*8 + r;
    const int b = mg >> 10, j = mg & 1023;
    const i64 n = (i64)b*Tn + LEAF0 + j;
    const float i_ = acc0[r]+bi, o_ = acc1[r]+bo, u_ = acc2[r]+bu;
    const float cn = sigm(i_)*tanhf(u_) + c0[n*Hd + hh];
    cb[n*Hd + hh] = cn;
    h[n*Hd + hh] = sigm(o_)*tanhf(cn);
  }
}

// Internal level: nodes t = s..e-1, children at e+2j, e+2j+1 (h_cat contiguous 512 floats).
// 5 strips: i, o, u, f_left, f_right. K=512.
__global__ __launch_bounds__(256)
void level_kernel(const float* __restrict__ Wt, const float* __restrict__ b_iou,
                  const float* __restrict__ U_f_b, float* __restrict__ h,
                  float* __restrict__ cb, int s, int e, int logn){
  __shared__ __align__(16) float A[512*MT];   // [k][m], 64KB
  const int tid = threadIdx.x;
  const int nm1 = (1<<logn)-1;
  {
    const int m = tid >> 3, q = tid & 7;
    const int mg = blockIdx.x*MT + m;
    const int b = mg >> logn, j = mg & nm1;
    const float* row = h + ((i64)b*Tn + e + 2*j)*Hd;   // [h_left ; h_right], contiguous
    #pragma unroll
    for (int i=0;i<16;i++){
      const int k = i*32 + q*4;
      float4 v = *(const float4*)(row + k);
      A[(k+0)*MT+m]=v.x; A[(k+1)*MT+m]=v.y; A[(k+2)*MT+m]=v.z; A[(k+3)*MT+m]=v.w;
    }
  }
  __syncthreads();
  const int tx = tid & 63, ty = tid >> 6;
  const int hh = blockIdx.y*64 + tx;
  float acc0[8], acc1[8], acc2[8], acc3[8], acc4[8];
  #pragma unroll
  for (int r=0;r<8;r++){ acc0[r]=0.f; acc1[r]=0.f; acc2[r]=0.f; acc3[r]=0.f; acc4[r]=0.f; }
  const float* wp = Wt + hh;
  #pragma unroll 2
  for (int k=0;k<512;k++){
    const float* wk = wp + k*1280;
    const float w0=wk[0], w1=wk[256], w2=wk[512], w3=wk[768], w4=wk[1024];
    float a[8];
    *(float4*)(a)   = *(const float4*)&A[k*MT + ty*8];
    *(float4*)(a+4) = *(const float4*)&A[k*MT + ty*8 + 4];
    #pragma unroll
    for (int r=0;r<8;r++){
      acc0[r] += a[r]*w0;
      acc1[r] += a[r]*w1;
      acc2[r] += a[r]*w2;
      acc3[r] += a[r]*w3;
      acc4[r] += a[r]*w4;
    }
  }
  const float bi=b_iou[hh], bo=b_iou[256+hh], bu=b_iou[512+hh];
  const float bl=U_f_b[hh], br=U_f_b[256+hh];
  #pragma unroll
  for (int r=0;r<8;r++){
    const int mg = blockIdx.x*MT + ty*8 + r;
    const int b = mg >> logn, j = mg & nm1;
    const i64 base = (i64)b*Tn;
    const i64 cidx = (base + e + 2*j)*Hd + hh;
    const float cl = cb[cidx], crr = cb[cidx + Hd];
    const float i_=acc0[r]+bi, o_=acc1[r]+bo, u_=acc2[r]+bu;
    const float fl=acc3[r]+bl, fr=acc4[r]+br;
    const float cn = sigm(i_)*tanhf(u_) + sigm(fl)*cl + sigm(fr)*crr;
    const i64 oidx = (base + s + j)*Hd + hh;
    cb[oidx] = cn;
    h[oidx] = sigm(o_)*tanhf(cn);
  }
}

__global__ __launch_bounds__(256)
void root_kernel(const float* __restrict__ h, const float* __restrict__ cb,
                 float* __restrict__ out_tail){
  const int b = blockIdx.x, hh = threadIdx.x;
  out_tail[b*Hd + hh]         = h[(i64)b*Tn*Hd + hh];
  out_tail[Bb*Hd + b*Hd + hh] = cb[(i64)b*Tn*Hd + hh];
}

extern "C" void kernel_launch(void* const* d_in, const int* in_sizes, int n_in,
                              void* d_out, int out_size, void* d_ws, size_t ws_size,
                              hipStream_t stream){
  const int*   wordid = (const int*)  d_in[0];
  const float* c0     = (const float*)d_in[3];
  const float* emb    = (const float*)d_in[6];
  const float* W_iou  = (const float*)d_in[7];
  const float* U_iou  = (const float*)d_in[8];
  const float* b_iou  = (const float*)d_in[9];
  const float* U_f_w  = (const float*)d_in[10];
  const float* U_f_b  = (const float*)d_in[11];

  float* h        = (float*)d_out;                 // tree_output = h, (B,T,H)
  float* out_tail = h + (i64)Bb*Tn*Hd;             // root_h then root_c
  float* cb  = (float*)d_ws;                       // c, (B,T,H)
  float* WtI = cb + (i64)Bb*Tn*Hd;                 // 512*1280
  float* WtL = WtI + 512*1280;                     // 256*768

  hipLaunchKernelGGL(wt_kernel, dim3(2560), dim3(256), 0, stream,
                     U_iou, U_f_w, W_iou, WtI, WtL);
  hipLaunchKernelGGL(leaf_kernel, dim3(2048,4), dim3(256), 0, stream,
                     wordid, emb, WtL, b_iou, c0, h, cb);
  for (int d = 9; d >= 0; --d){
    const int n = 1<<d, s = n-1, e = 2*n-1;
    hipLaunchKernelGGL(level_kernel, dim3(2*n,4), dim3(256), 0, stream,
                       WtI, b_iou, U_f_b, h, cb, s, e, d);
  }
  hipLaunchKernelGGL(root_kernel, dim3(64), dim3(256), 0, stream, h, cb, out_tail);
}

// Round 2
// 542.011 us; speedup vs baseline: 4.6351x; 4.6351x over previous
//
#include <hip/hip_runtime.h>
#include <math.h>

typedef long long i64;
typedef short short8v __attribute__((ext_vector_type(8)));
typedef float float4v __attribute__((ext_vector_type(4)));

#define Hd 256
#define Bb 64
#define Tn 2047
#define LEAF0 1023
#define NTH 33538048LL   // B*T*H elements

__device__ __forceinline__ float sigm(float x){ return 1.0f/(1.0f+__expf(-x)); }
__device__ __forceinline__ float bf2f(unsigned short s){
  union { unsigned u; float f; } v; v.u = ((unsigned)s)<<16; return v.f; }
__device__ __forceinline__ short f2bf(float f){
  union { float f; unsigned u; } v; v.f = f;
  unsigned r = v.u + 0x7FFF + ((v.u>>16)&1);
  return (short)(r>>16); }

#define GL2LDS(gp, lp) __builtin_amdgcn_global_load_lds( \
  (const __attribute__((address_space(1))) void*)(gp), \
  (__attribute__((address_space(3))) void*)(lp), 16, 0, 0)

// ---------------------------------------------------------------------------
// Pack weights to bf16 in MFMA fragment order.
// Wt2I[hhb][kt<16][nr<20][lane<64][8] : levels, K=512, cols j = strip*256 + hhb*64 + g*16 + (lane&15),
//   nr = g*5 + strip, k = kt*32 + (lane>>4)*8 + e; W[j][k] = j<768 ? U_iou : U_f_w[j-768]
// Wt2L[hhb][kt<8][nr<12][lane<64][8] : leaf, K=256, nr = g*3 + strip, W_iou[j][k]
// ---------------------------------------------------------------------------
__global__ __launch_bounds__(256)
void wt2_kernel(const float* __restrict__ W_iou, const float* __restrict__ U_iou,
                const float* __restrict__ U_f_w,
                short* __restrict__ Wt2I, short* __restrict__ Wt2L){
  int t = blockIdx.x*256 + threadIdx.x;
  if (blockIdx.x < 320){
    int lane = t & 63, rest = t >> 6;
    int nr = rest % 20; int rest2 = rest / 20;
    int kt = rest2 & 15, hhb = rest2 >> 4;
    int g = nr/5, strip = nr - g*5;
    int j = strip*256 + hhb*64 + g*16 + (lane&15);
    int k0 = kt*32 + (lane>>4)*8;
    const float* src = (j < 768) ? (U_iou + (i64)j*512 + k0)
                                 : (U_f_w + (i64)(j-768)*512 + k0);
    short* dst = Wt2I + (i64)t*8;
    #pragma unroll
    for (int e=0;e<8;e++) dst[e] = f2bf(src[e]);
  } else {
    int t2 = t - 320*256;
    int lane = t2 & 63, rest = t2 >> 6;
    int nr = rest % 12; int rest2 = rest / 12;
    int kt = rest2 & 7, hhb = rest2 >> 3;
    int g = nr/3, strip = nr - g*3;
    int j = strip*256 + hhb*64 + g*16 + (lane&15);
    int k0 = kt*32 + (lane>>4)*8;
    const float* src = W_iou + (i64)j*256 + k0;
    short* dst = Wt2L + (i64)t2*8;
    #pragma unroll
    for (int e=0;e<8;e++) dst[e] = f2bf(src[e]);
  }
}

// Gather+sum 5 embeddings per leaf -> bf16, stored into hb's LEAF rows
// (overwritten by hconv after the leaf GEMM consumes them).
__global__ __launch_bounds__(256)
void wemb_kernel(const int* __restrict__ wordid, const float* __restrict__ emb,
                 short* __restrict__ hb){
  int id = blockIdx.x*256 + threadIdx.x;   // 65536 rows x 32 thr, 8 cols each
  int row = id >> 5, q = id & 31;
  int b = row >> 10, j = row & 1023;
  i64 n = (i64)b*Tn + LEAF0 + j;
  const int* wid = wordid + n*5;
  float s[8];
  #pragma unroll
  for (int e=0;e<8;e++) s[e] = 0.f;
  #pragma unroll
  for (int l=0;l<5;l++){
    const float* er = emb + (i64)wid[l]*Hd + q*8;
    float4 v0 = *(const float4*)(er);
    float4 v1 = *(const float4*)(er+4);
    s[0]+=v0.x; s[1]+=v0.y; s[2]+=v0.z; s[3]+=v0.w;
    s[4]+=v1.x; s[5]+=v1.y; s[6]+=v1.z; s[7]+=v1.w;
  }
  short o[8];
  #pragma unroll
  for (int e=0;e<8;e++) o[e] = f2bf(s[e]);
  *(short8v*)(hb + n*Hd + q*8) = *(short8v*)o;
}

// Leaf GEMM: M=65536 (leaf rows), K=256, cols = 64hh x {i,o,u}. Block 128 x 192.
__global__ __launch_bounds__(512)
void leaf_gemm(const short* __restrict__ hb, const short* __restrict__ WB,
               const float* __restrict__ b_iou, const float* __restrict__ c0,
               float* __restrict__ hOut, short* __restrict__ cbb){
  __shared__ __align__(16) short Ab[2][8*512];
  __shared__ __align__(16) short Bbuf[2][12*512];
  const int tid = threadIdx.x;
  const int lane = tid & 63, w = tid >> 6;
  const int wm = w >> 2, wg = w & 3;
  const int m0 = blockIdx.x*128;
  const int hhb = blockIdx.y;

  float4v acc[4][3];
  #pragma unroll
  for (int mr=0;mr<4;mr++)
    #pragma unroll
    for (int s=0;s<3;s++){ float4v z = {0.f,0.f,0.f,0.f}; acc[mr][s] = z; }

  const int mA = m0 + w*16 + (lane&15);
  const int bA = mA >> 10, jA = mA & 1023;
  const short* gA = hb + ((i64)bA*Tn + LEAF0 + jA)*Hd + (lane>>4)*8;

  int cur = 0;
  // prologue kt=0
  {
    GL2LDS(gA, &Ab[0][w*512]);
    const short* baseB = WB + ((i64)(hhb*8 + 0)*12)*512 + lane*8;
    GL2LDS(baseB + (i64)w*512, &Bbuf[0][w*512]);
    if (w < 4) GL2LDS(baseB + (i64)(8+w)*512, &Bbuf[0][(8+w)*512]);
  }
  for (int kt=0; kt<8; ++kt){
    __syncthreads();
    if (kt+1 < 8){
      int nxt = cur^1;
      GL2LDS(gA + (kt+1)*32, &Ab[nxt][w*512]);
      const short* baseB = WB + ((i64)(hhb*8 + kt+1)*12)*512 + lane*8;
      GL2LDS(baseB + (i64)w*512, &Bbuf[nxt][w*512]);
      if (w < 4) GL2LDS(baseB + (i64)(8+w)*512, &Bbuf[nxt][(8+w)*512]);
    }
    short8v bfr[3];
    #pragma unroll
    for (int s=0;s<3;s++) bfr[s] = *(const short8v*)&Bbuf[cur][(wg*3+s)*512 + lane*8];
    #pragma unroll
    for (int mr=0;mr<4;mr++){
      short8v a = *(const short8v*)&Ab[cur][(wm*4+mr)*512 + lane*8];
      #pragma unroll
      for (int s=0;s<3;s++)
        acc[mr][s] = __builtin_amdgcn_mfma_f32_16x16x32_bf16(a, bfr[s], acc[mr][s], 0, 0, 0);
    }
    cur ^= 1;
  }

  const int hcol = hhb*64 + wg*16 + (lane&15);
  const float bi = b_iou[hcol], bo = b_iou[256+hcol], bu = b_iou[512+hcol];
  #pragma unroll
  for (int mr=0;mr<4;mr++){
    const int mgb = m0 + wm*64 + mr*16 + ((lane>>4)<<2);
    #pragma unroll
    for (int r=0;r<4;r++){
      const int m = mgb + r;
      const int b = m >> 10, j = m & 1023;
      const i64 n = (i64)b*Tn + LEAF0 + j;
      const float i_ = acc[mr][0][r] + bi;
      const float o_ = acc[mr][1][r] + bo;
      const float u_ = acc[mr][2][r] + bu;
      const float cn = sigm(i_)*tanhf(u_) + c0[n*Hd + hcol];
      cbb[n*Hd + hcol] = f2bf(cn);
      hOut[n*Hd + hcol] = sigm(o_)*tanhf(cn);
    }
  }
}

// Convert leaf h (fp32 in d_out) -> bf16 hb rows (after leaf_gemm finished).
__global__ __launch_bounds__(256)
void hconv_kernel(const float* __restrict__ hOut, short* __restrict__ hb){
  int id = blockIdx.x*256 + threadIdx.x;
  i64 idx = (i64)id*8;
  int row = (int)(idx >> 8), col = (int)(idx & 255);
  int b = row >> 10, j = row & 1023;
  i64 off = ((i64)b*Tn + LEAF0 + j)*Hd + col;
  const float* src = hOut + off;
  float4 v0 = *(const float4*)src;
  float4 v1 = *(const float4*)(src+4);
  short o[8] = { f2bf(v0.x),f2bf(v0.y),f2bf(v0.z),f2bf(v0.w),
                 f2bf(v1.x),f2bf(v1.y),f2bf(v1.z),f2bf(v1.w) };
  *(short8v*)(hb + off) = *(short8v*)o;
}

// Internal level: M=64n, K=512 (children h contiguous 512 bf16), cols = 64hh x {i,o,u,fl,fr}.
__global__ __launch_bounds__(512)
void level_gemm(const short* __restrict__ WB,
                const float* __restrict__ b_iou, const float* __restrict__ U_f_b,
                float* __restrict__ hOut, short* __restrict__ hb, short* __restrict__ cbb,
                float* __restrict__ outRoot, int s0, int e0, int logn){
  __shared__ __align__(16) short Ab[2][8*512];
  __shared__ __align__(16) short Bbuf[2][20*512];
  const int tid = threadIdx.x;
  const int lane = tid & 63, w = tid >> 6;
  const int wm = w >> 2, wg = w & 3;
  const int m0 = blockIdx.x*128;
  const int hhb = blockIdx.y;
  const int Mtot = Bb << logn;
  const int nm1 = (1<<logn)-1;

  float4v acc[4][5];
  #pragma unroll
  for (int mr=0;mr<4;mr++)
    #pragma unroll
    for (int s=0;s<5;s++){ float4v z = {0.f,0.f,0.f,0.f}; acc[mr][s] = z; }

  int mA = m0 + w*16 + (lane&15);
  if (mA >= Mtot) mA = Mtot-1;
  const int bA = mA >> logn, jA = mA & nm1;
  const short* gA = hb + ((i64)bA*Tn + e0)*Hd + (i64)jA*512 + (lane>>4)*8;

  int cur = 0;
  {
    GL2LDS(gA, &Ab[0][w*512]);
    const short* baseB = WB + ((i64)(hhb*16 + 0)*20)*512 + lane*8;
    GL2LDS(baseB + (i64)w*512, &Bbuf[0][w*512]);
    GL2LDS(baseB + (i64)(8+w)*512, &Bbuf[0][(8+w)*512]);
    if (w < 4) GL2LDS(baseB + (i64)(16+w)*512, &Bbuf[0][(16+w)*512]);
  }
  for (int kt=0; kt<16; ++kt){
    __syncthreads();
    if (kt+1 < 16){
      int nxt = cur^1;
      GL2LDS(gA + (kt+1)*32, &Ab[nxt][w*512]);
      const short* baseB = WB + ((i64)(hhb*16 + kt+1)*20)*512 + lane*8;
      GL2LDS(baseB + (i64)w*512, &Bbuf[nxt][w*512]);
      GL2LDS(baseB + (i64)(8+w)*512, &Bbuf[nxt][(8+w)*512]);
      if (w < 4) GL2LDS(baseB + (i64)(16+w)*512, &Bbuf[nxt][(16+w)*512]);
    }
    short8v bfr[5];
    #pragma unroll
    for (int s=0;s<5;s++) bfr[s] = *(const short8v*)&Bbuf[cur][(wg*5+s)*512 + lane*8];
    #pragma unroll
    for (int mr=0;mr<4;mr++){
      short8v a = *(const short8v*)&Ab[cur][(wm*4+mr)*512 + lane*8];
      #pragma unroll
      for (int s=0;s<5;s++)
        acc[mr][s] = __builtin_amdgcn_mfma_f32_16x16x32_bf16(a, bfr[s], acc[mr][s], 0, 0, 0);
    }
    cur ^= 1;
  }

  const int hcol = hhb*64 + wg*16 + (lane&15);
  const float bi = b_iou[hcol], bo = b_iou[256+hcol], bu = b_iou[512+hcol];
  const float bfl = U_f_b[hcol], bfr2 = U_f_b[256+hcol];
  #pragma unroll
  for (int mr=0;mr<4;mr++){
    const int mgb = m0 + wm*64 + mr*16 + ((lane>>4)<<2);
    #pragma unroll
    for (int r=0;r<4;r++){
      const int m = mgb + r;
      if (m < Mtot){
        const int b = m >> logn, j = m & nm1;
        const i64 base = (i64)b*Tn;
        const i64 cidx = (base + e0 + 2*j)*Hd + hcol;
        const float cl = bf2f((unsigned short)cbb[cidx]);
        const float cr = bf2f((unsigned short)cbb[cidx + Hd]);
        const float i_ = acc[mr][0][r]+bi, o_ = acc[mr][1][r]+bo, u_ = acc[mr][2][r]+bu;
        const float fl = acc[mr][3][r]+bfl, fr = acc[mr][4][r]+bfr2;
        const float cn = sigm(i_)*tanhf(u_) + sigm(fl)*cl + sigm(fr)*cr;
        const float hv = sigm(o_)*tanhf(cn);
        const i64 oidx = (base + s0 + j)*Hd + hcol;
        cbb[oidx] = f2bf(cn);
        hb[oidx]  = f2bf(hv);
        hOut[oidx] = hv;
        if (s0 == 0){
          outRoot[b*Hd + hcol] = hv;
          outRoot[Bb*Hd + b*Hd + hcol] = cn;
        }
      }
    }
  }
}

extern "C" void kernel_launch(void* const* d_in, const int* in_sizes, int n_in,
                              void* d_out, int out_size, void* d_ws, size_t ws_size,
                              hipStream_t stream){
  const int*   wordid = (const int*)  d_in[0];
  const float* c0     = (const float*)d_in[3];
  const float* emb    = (const float*)d_in[6];
  const float* W_iou  = (const float*)d_in[7];
  const float* U_iou  = (const float*)d_in[8];
  const float* b_iou  = (const float*)d_in[9];
  const float* U_f_w  = (const float*)d_in[10];
  const float* U_f_b  = (const float*)d_in[11];

  float* hOut    = (float*)d_out;            // (B,T,H) fp32
  float* outRoot = hOut + NTH;               // root_h then root_c
  short* cbb  = (short*)d_ws;                // c  bf16 (B,T,H)
  short* hb   = cbb + NTH;                   // h  bf16 (B,T,H); leaf rows hold wemb pre-GEMM
  short* Wt2I = hb + NTH;                    // 4*16*20*64*8 = 655360 shorts
  short* Wt2L = Wt2I + 655360;               // 4*8*12*64*8  = 196608 shorts

  hipLaunchKernelGGL(wt2_kernel, dim3(416), dim3(256), 0, stream,
                     W_iou, U_iou, U_f_w, Wt2I, Wt2L);
  hipLaunchKernelGGL(wemb_kernel, dim3(8192), dim3(256), 0, stream, wordid, emb, hb);
  hipLaunchKernelGGL(leaf_gemm, dim3(512,4), dim3(512), 0, stream,
                     hb, Wt2L, b_iou, c0, hOut, cbb);
  hipLaunchKernelGGL(hconv_kernel, dim3(8192), dim3(256), 0, stream, hOut, hb);
  for (int d = 9; d >= 0; --d){
    const int n = 1<<d, s = n-1, e = 2*n-1;
    int bm = (64*n + 127)/128; if (bm < 1) bm = 1;
    hipLaunchKernelGGL(level_gemm, dim3(bm,4), dim3(512), 0, stream,
                       Wt2I, b_iou, U_f_b, hOut, hb, cbb, outRoot, s, e, d);
  }
}

// Round 3
// 456.472 us; speedup vs baseline: 5.5037x; 1.1874x over previous
//
#include <hip/hip_runtime.h>
#include <math.h>

typedef long long i64;
typedef short short8v __attribute__((ext_vector_type(8)));
typedef float float4v __attribute__((ext_vector_type(4)));

#define Hd 256
#define Bb 64
#define Tn 2047
#define LEAF0 1023
#define NTH 33538048LL   // B*T*H elements

__device__ __forceinline__ float frcp(float x){ return __builtin_amdgcn_rcpf(x); }
__device__ __forceinline__ float sigm(float x){ return frcp(1.0f+__expf(-x)); }
__device__ __forceinline__ float ftanh(float x){ return 1.0f - 2.0f*frcp(__expf(2.0f*x)+1.0f); }
__device__ __forceinline__ float bf2f(unsigned short s){
  union { unsigned u; float f; } v; v.u = ((unsigned)s)<<16; return v.f; }
__device__ __forceinline__ short f2bf(float f){
  union { float f; unsigned u; } v; v.f = f;
  unsigned r = v.u + 0x7FFF + ((v.u>>16)&1);
  return (short)(r>>16); }

#define GL2LDS(gp, lp) __builtin_amdgcn_global_load_lds( \
  (const __attribute__((address_space(1))) void*)(gp), \
  (__attribute__((address_space(3))) void*)(lp), 16, 0, 0)

// ---------------------------------------------------------------------------
// Pack weights to bf16 in MFMA fragment order.
// Wt2I[hhb][kt<16][nr<20][lane<64][8] : levels, K=512, cols j = strip*256 + hhb*64 + g*16 + (lane&15),
//   nr = g*5 + strip, k = kt*32 + (lane>>4)*8 + e
// Wt2L[hhb][kt<8][nr<12][lane<64][8] : leaf, K=256, nr = g*3 + strip
// ---------------------------------------------------------------------------
__global__ __launch_bounds__(256)
void wt2_kernel(const float* __restrict__ W_iou, const float* __restrict__ U_iou,
                const float* __restrict__ U_f_w,
                short* __restrict__ Wt2I, short* __restrict__ Wt2L){
  int t = blockIdx.x*256 + threadIdx.x;
  if (blockIdx.x < 320){
    int lane = t & 63, rest = t >> 6;
    int nr = rest % 20; int rest2 = rest / 20;
    int kt = rest2 & 15, hhb = rest2 >> 4;
    int g = nr/5, strip = nr - g*5;
    int j = strip*256 + hhb*64 + g*16 + (lane&15);
    int k0 = kt*32 + (lane>>4)*8;
    const float* src = (j < 768) ? (U_iou + (i64)j*512 + k0)
                                 : (U_f_w + (i64)(j-768)*512 + k0);
    short* dst = Wt2I + (i64)t*8;
    #pragma unroll
    for (int e=0;e<8;e++) dst[e] = f2bf(src[e]);
  } else {
    int t2 = t - 320*256;
    int lane = t2 & 63, rest = t2 >> 6;
    int nr = rest % 12; int rest2 = rest / 12;
    int kt = rest2 & 7, hhb = rest2 >> 3;
    int g = nr/3, strip = nr - g*3;
    int j = strip*256 + hhb*64 + g*16 + (lane&15);
    int k0 = kt*32 + (lane>>4)*8;
    const float* src = W_iou + (i64)j*256 + k0;
    short* dst = Wt2L + (i64)t2*8;
    #pragma unroll
    for (int e=0;e<8;e++) dst[e] = f2bf(src[e]);
  }
}

// Gather+sum 5 embeddings per leaf -> bf16, stored into hb's LEAF rows.
__global__ __launch_bounds__(256)
void wemb_kernel(const int* __restrict__ wordid, const float* __restrict__ emb,
                 short* __restrict__ hb){
  int id = blockIdx.x*256 + threadIdx.x;   // 65536 rows x 32 thr, 8 cols each
  int row = id >> 5, q = id & 31;
  int b = row >> 10, j = row & 1023;
  i64 n = (i64)b*Tn + LEAF0 + j;
  const int* wid = wordid + n*5;
  float s[8];
  #pragma unroll
  for (int e=0;e<8;e++) s[e] = 0.f;
  #pragma unroll
  for (int l=0;l<5;l++){
    const float* er = emb + (i64)wid[l]*Hd + q*8;
    float4 v0 = *(const float4*)(er);
    float4 v1 = *(const float4*)(er+4);
    s[0]+=v0.x; s[1]+=v0.y; s[2]+=v0.z; s[3]+=v0.w;
    s[4]+=v1.x; s[5]+=v1.y; s[6]+=v1.z; s[7]+=v1.w;
  }
  short o[8];
  #pragma unroll
  for (int e=0;e<8;e++) o[e] = f2bf(s[e]);
  *(short8v*)(hb + n*Hd + q*8) = *(short8v*)o;
}

// Leaf GEMM: M=65536, K=256, cols = 64hh x {i,o,u}. Block 128 rows; B direct from L2.
__global__ __launch_bounds__(512, 4)
void leaf_gemm(const short* __restrict__ hb, const short* __restrict__ WB,
               const float* __restrict__ b_iou, const float* __restrict__ c0,
               float* __restrict__ hOut, short* __restrict__ cbb){
  __shared__ __align__(16) short Ab[2][8*512];
  const int tid = threadIdx.x;
  const int lane = tid & 63, w = tid >> 6;
  const int wm = w >> 2, wg = w & 3;
  const int m0 = blockIdx.x*128;
  const int hhb = blockIdx.y;

  float4v acc[4][3];
  #pragma unroll
  for (int mr=0;mr<4;mr++)
    #pragma unroll
    for (int s=0;s<3;s++){ float4v z = {0.f,0.f,0.f,0.f}; acc[mr][s] = z; }

  const int mA = m0 + w*16 + (lane&15);
  const int bA = mA >> 10, jA = mA & 1023;
  const short* gA = hb + ((i64)bA*Tn + LEAF0 + jA)*Hd + (lane>>4)*8;
  const short* gB0 = WB + (i64)hhb*96*512 + (i64)(wg*3)*512 + lane*8;

  int cur = 0;
  GL2LDS(gA, &Ab[0][w*512]);
  #pragma unroll 2
  for (int kt=0; kt<8; ++kt){
    __syncthreads();
    if (kt+1 < 8) GL2LDS(gA + (kt+1)*32, &Ab[cur^1][w*512]);
    const short* bp = gB0 + (i64)kt*12*512;
    short8v bfr[3];
    #pragma unroll
    for (int s=0;s<3;s++) bfr[s] = *(const short8v*)(bp + (i64)s*512);
    #pragma unroll
    for (int mr=0;mr<4;mr++){
      short8v a = *(const short8v*)&Ab[cur][(wm*4+mr)*512 + lane*8];
      #pragma unroll
      for (int s=0;s<3;s++)
        acc[mr][s] = __builtin_amdgcn_mfma_f32_16x16x32_bf16(a, bfr[s], acc[mr][s], 0, 0, 0);
    }
    cur ^= 1;
  }

  const int hcol = hhb*64 + wg*16 + (lane&15);
  const float bi = b_iou[hcol], bo = b_iou[256+hcol], bu = b_iou[512+hcol];
  #pragma unroll
  for (int mr=0;mr<4;mr++){
    const int mgb = m0 + wm*64 + mr*16 + ((lane>>4)<<2);
    #pragma unroll
    for (int r=0;r<4;r++){
      const int m = mgb + r;
      const int b = m >> 10, j = m & 1023;
      const i64 n = (i64)b*Tn + LEAF0 + j;
      const float i_ = acc[mr][0][r] + bi;
      const float o_ = acc[mr][1][r] + bo;
      const float u_ = acc[mr][2][r] + bu;
      const float cn = sigm(i_)*ftanh(u_) + c0[n*Hd + hcol];
      cbb[n*Hd + hcol] = f2bf(cn);
      hOut[n*Hd + hcol] = sigm(o_)*ftanh(cn);
    }
  }
}

// Convert leaf h (fp32 in d_out) -> bf16 hb rows.
__global__ __launch_bounds__(256)
void hconv_kernel(const float* __restrict__ hOut, short* __restrict__ hb){
  int id = blockIdx.x*256 + threadIdx.x;
  i64 idx = (i64)id*8;
  int row = (int)(idx >> 8), col = (int)(idx & 255);
  int b = row >> 10, j = row & 1023;
  i64 off = ((i64)b*Tn + LEAF0 + j)*Hd + col;
  const float* src = hOut + off;
  float4 v0 = *(const float4*)src;
  float4 v1 = *(const float4*)(src+4);
  short o[8] = { f2bf(v0.x),f2bf(v0.y),f2bf(v0.z),f2bf(v0.w),
                 f2bf(v1.x),f2bf(v1.y),f2bf(v1.z),f2bf(v1.w) };
  *(short8v*)(hb + off) = *(short8v*)o;
}

// Internal level: M=64n, K=512, cols = 64hh x {i,o,u,fl,fr}. B direct from L2.
__global__ __launch_bounds__(512, 4)
void level_gemm(const short* __restrict__ WB,
                const float* __restrict__ b_iou, const float* __restrict__ U_f_b,
                float* __restrict__ hOut, short* __restrict__ hb, short* __restrict__ cbb,
                float* __restrict__ outRoot, int s0, int e0, int logn){
  __shared__ __align__(16) short Ab[2][8*512];
  const int tid = threadIdx.x;
  const int lane = tid & 63, w = tid >> 6;
  const int wm = w >> 2, wg = w & 3;
  const int m0 = blockIdx.x*128;
  const int hhb = blockIdx.y;
  const int Mtot = Bb << logn;
  const int nm1 = (1<<logn)-1;

  float4v acc[4][5];
  #pragma unroll
  for (int mr=0;mr<4;mr++)
    #pragma unroll
    for (int s=0;s<5;s++){ float4v z = {0.f,0.f,0.f,0.f}; acc[mr][s] = z; }

  int mA = m0 + w*16 + (lane&15);
  if (mA >= Mtot) mA = Mtot-1;
  const int bA = mA >> logn, jA = mA & nm1;
  const short* gA = hb + ((i64)bA*Tn + e0)*Hd + (i64)jA*512 + (lane>>4)*8;
  const short* gB0 = WB + (i64)hhb*320*512 + (i64)(wg*5)*512 + lane*8;

  int cur = 0;
  GL2LDS(gA, &Ab[0][w*512]);
  #pragma unroll 2
  for (int kt=0; kt<16; ++kt){
    __syncthreads();
    if (kt+1 < 16) GL2LDS(gA + (kt+1)*32, &Ab[cur^1][w*512]);
    const short* bp = gB0 + (i64)kt*20*512;
    short8v bfr[5];
    #pragma unroll
    for (int s=0;s<5;s++) bfr[s] = *(const short8v*)(bp + (i64)s*512);
    #pragma unroll
    for (int mr=0;mr<4;mr++){
      short8v a = *(const short8v*)&Ab[cur][(wm*4+mr)*512 + lane*8];
      #pragma unroll
      for (int s=0;s<5;s++)
        acc[mr][s] = __builtin_amdgcn_mfma_f32_16x16x32_bf16(a, bfr[s], acc[mr][s], 0, 0, 0);
    }
    cur ^= 1;
  }

  const int hcol = hhb*64 + wg*16 + (lane&15);
  const float bi = b_iou[hcol], bo = b_iou[256+hcol], bu = b_iou[512+hcol];
  const float bfl = U_f_b[hcol], bfr2 = U_f_b[256+hcol];
  #pragma unroll
  for (int mr=0;mr<4;mr++){
    const int mgb = m0 + wm*64 + mr*16 + ((lane>>4)<<2);
    #pragma unroll
    for (int r=0;r<4;r++){
      const int m = mgb + r;
      if (m < Mtot){
        const int b = m >> logn, j = m & nm1;
        const i64 base = (i64)b*Tn;
        const i64 cidx = (base + e0 + 2*j)*Hd + hcol;
        const float cl = bf2f((unsigned short)cbb[cidx]);
        const float cr = bf2f((unsigned short)cbb[cidx + Hd]);
        const float i_ = acc[mr][0][r]+bi, o_ = acc[mr][1][r]+bo, u_ = acc[mr][2][r]+bu;
        const float fl = acc[mr][3][r]+bfl, fr = acc[mr][4][r]+bfr2;
        const float cn = sigm(i_)*ftanh(u_) + sigm(fl)*cl + sigm(fr)*cr;
        const float hv = sigm(o_)*ftanh(cn);
        const i64 oidx = (base + s0 + j)*Hd + hcol;
        cbb[oidx] = f2bf(cn);
        hb[oidx]  = f2bf(hv);
        hOut[oidx] = hv;
        if (s0 == 0){
          outRoot[b*Hd + hcol] = hv;
          outRoot[Bb*Hd + b*Hd + hcol] = cn;
        }
      }
    }
  }
}

extern "C" void kernel_launch(void* const* d_in, const int* in_sizes, int n_in,
                              void* d_out, int out_size, void* d_ws, size_t ws_size,
                              hipStream_t stream){
  const int*   wordid = (const int*)  d_in[0];
  const float* c0     = (const float*)d_in[3];
  const float* emb    = (const float*)d_in[6];
  const float* W_iou  = (const float*)d_in[7];
  const float* U_iou  = (const float*)d_in[8];
  const float* b_iou  = (const float*)d_in[9];
  const float* U_f_w  = (const float*)d_in[10];
  const float* U_f_b  = (const float*)d_in[11];

  float* hOut    = (float*)d_out;            // (B,T,H) fp32
  float* outRoot = hOut + NTH;               // root_h then root_c
  short* cbb  = (short*)d_ws;                // c  bf16 (B,T,H)
  short* hb   = cbb + NTH;                   // h  bf16 (B,T,H); leaf rows hold wemb pre-GEMM
  short* Wt2I = hb + NTH;                    // 4*16*20*64*8 = 655360 shorts
  short* Wt2L = Wt2I + 655360;               // 4*8*12*64*8  = 196608 shorts

  hipLaunchKernelGGL(wt2_kernel, dim3(416), dim3(256), 0, stream,
                     W_iou, U_iou, U_f_w, Wt2I, Wt2L);
  hipLaunchKernelGGL(wemb_kernel, dim3(8192), dim3(256), 0, stream, wordid, emb, hb);
  hipLaunchKernelGGL(leaf_gemm, dim3(512,4), dim3(512), 0, stream,
                     hb, Wt2L, b_iou, c0, hOut, cbb);
  hipLaunchKernelGGL(hconv_kernel, dim3(8192), dim3(256), 0, stream, hOut, hb);
  for (int d = 9; d >= 0; --d){
    const int n = 1<<d, s = n-1, e = 2*n-1;
    int bm = (64*n + 127)/128; if (bm < 1) bm = 1;
    hipLaunchKernelGGL(level_gemm, dim3(bm,4), dim3(512), 0, stream,
                       Wt2I, b_iou, U_f_b, hOut, hb, cbb, outRoot, s, e, d);
  }
}